// Round 1
// baseline (229.167 us; speedup 1.0000x reference)
//
#include <hip/hip_runtime.h>

// Fused: z = x @ W^T + b_lin; y = swish(z) + b_ex; GroupNorm(32 groups) * gn_w + gn_b
// x: [8192, 2048] f32, W: [4096, 2048] f32, out: [8192, 4096] f32
// Strategy: convert x,W to bf16 in d_ws, then one MFMA GEMM with GN fused in
// the epilogue (N-tile 128 == exactly one GroupNorm group).

typedef __attribute__((ext_vector_type(8))) short short8;
typedef __attribute__((ext_vector_type(4))) float f32x4;

#define M_DIM 8192
#define N_DIM 4096
#define K_DIM 2048
#define BM 128
#define BN 128
#define BK 32

// ---------------- f32 -> bf16 (RNE) convert, 8 elems/thread ----------------
__global__ void f32_to_bf16_k(const float* __restrict__ in, ushort* __restrict__ out, int n8) {
    int i = blockIdx.x * blockDim.x + threadIdx.x;
    if (i >= n8) return;
    const float4* p = (const float4*)in + 2 * (size_t)i;
    float4 a = p[0], b = p[1];
    float v[8] = {a.x, a.y, a.z, a.w, b.x, b.y, b.z, b.w};
    ushort r[8];
#pragma unroll
    for (int j = 0; j < 8; ++j) {
        unsigned u = __float_as_uint(v[j]);
        r[j] = (ushort)((u + 0x7fffu + ((u >> 16) & 1u)) >> 16);  // round-nearest-even
    }
    uint4 o;
    o.x = (unsigned)r[0] | ((unsigned)r[1] << 16);
    o.y = (unsigned)r[2] | ((unsigned)r[3] << 16);
    o.z = (unsigned)r[4] | ((unsigned)r[5] << 16);
    o.w = (unsigned)r[6] | ((unsigned)r[7] << 16);
    ((uint4*)out)[i] = o;
}

// ---------------- fused GEMM + swish + GroupNorm ----------------
// Block: 256 threads = 4 waves (2x2), tile 128x128, BK=32.
// Wave (wrow,wcol) owns a 64x64 sub-tile as 4x4 fragments of 16x16.
// m97 structure: global_load_lds width=16 staging, 2-barrier K-loop.
__global__ __launch_bounds__(256) void gemm_swish_gn(
    const ushort* __restrict__ xb, const ushort* __restrict__ wb,
    const float* __restrict__ bias_lin, const float* __restrict__ bias_extra,
    const float* __restrict__ gn_w, const float* __restrict__ gn_b,
    float* __restrict__ out)
{
    __shared__ __align__(16) ushort sA[BM * BK];   // 8 KiB
    __shared__ __align__(16) ushort sB[BN * BK];   // 8 KiB
    __shared__ float sred[2][2][BM];               // [stat][wcol][row] partial sums

    const int t = threadIdx.x;
    const int w = t >> 6;        // wave id 0..3
    const int l = t & 63;        // lane
    const int wrow = w >> 1;     // 0..1 (M direction)
    const int wcol = w & 1;      // 0..1 (N direction)
    const int h = l >> 4;        // 0..3 (k-group / row-subblock)
    const int r = l & 15;        // 0..15

    const int brow = blockIdx.x;  // M tile
    const int bcol = blockIdx.y;  // N tile == GroupNorm group

    const size_t a_base = (size_t)brow * BM * K_DIM;
    const size_t b_base = (size_t)bcol * BN * K_DIM;

    f32x4 acc[4][4];
#pragma unroll
    for (int m = 0; m < 4; ++m)
#pragma unroll
        for (int n = 0; n < 4; ++n)
            acc[m][n] = f32x4{0.f, 0.f, 0.f, 0.f};

    for (int kt = 0; kt < K_DIM; kt += BK) {
        // ---- stage A,B tiles: 8 KiB each via global_load_lds width=16 ----
        // linear chunk c covers elements [c*8, c*8+8): row=c/4, kk=(c%4)*8
#pragma unroll
        for (int chunk = 0; chunk < 2; ++chunk) {
            int c = chunk * 256 + t;
            int row = c >> 2;
            int kk = (c & 3) << 3;
            const ushort* ga = xb + a_base + (size_t)row * K_DIM + kt + kk;
            const ushort* gw = wb + b_base + (size_t)row * K_DIM + kt + kk;
            // LDS dest: wave-uniform base; lanes land at base + lane*16B (linear layout)
            __builtin_amdgcn_global_load_lds(
                (const __attribute__((address_space(1))) void*)ga,
                (__attribute__((address_space(3))) void*)(sA + chunk * 2048 + w * 512),
                16, 0, 0);
            __builtin_amdgcn_global_load_lds(
                (const __attribute__((address_space(1))) void*)gw,
                (__attribute__((address_space(3))) void*)(sB + chunk * 2048 + w * 512),
                16, 0, 0);
        }
        __syncthreads();  // compiler drains vmcnt(0) before s_barrier

        short8 af[4], bfr[4];
#pragma unroll
        for (int m = 0; m < 4; ++m)
            af[m] = *(const short8*)&sA[(wrow * 64 + m * 16 + r) * BK + h * 8];
#pragma unroll
        for (int n = 0; n < 4; ++n)
            bfr[n] = *(const short8*)&sB[(wcol * 64 + n * 16 + r) * BK + h * 8];
#pragma unroll
        for (int m = 0; m < 4; ++m)
#pragma unroll
            for (int n = 0; n < 4; ++n)
                acc[m][n] = __builtin_amdgcn_mfma_f32_16x16x32_bf16(af[m], bfr[n], acc[m][n], 0, 0, 0);
        __syncthreads();  // LDS reads done before next stage overwrites
    }

    // ---- epilogue: bias + swish + extra bias, then GroupNorm over this tile ----
    // acc[m][n][j]: row = wrow*64 + m*16 + h*4 + j, col = wcol*64 + n*16 + r
    const int gcolbase = bcol * BN + wcol * 64;
    float bl[4], be[4], gwv[4], gbv[4];
#pragma unroll
    for (int n = 0; n < 4; ++n) {
        int col = gcolbase + n * 16 + r;
        bl[n] = bias_lin[col];
        be[n] = bias_extra[col];
        gwv[n] = gn_w[col];
        gbv[n] = gn_b[col];
    }

    float s1[4][4];  // [m][j] per-row partial sum over this lane's 4 cols
    float s2[4][4];
#pragma unroll
    for (int m = 0; m < 4; ++m)
#pragma unroll
        for (int j = 0; j < 4; ++j) { s1[m][j] = 0.f; s2[m][j] = 0.f; }

#pragma unroll
    for (int m = 0; m < 4; ++m)
#pragma unroll
        for (int n = 0; n < 4; ++n)
#pragma unroll
            for (int j = 0; j < 4; ++j) {
                float z = acc[m][n][j] + bl[n];
                float sw = z / (1.f + __expf(-z)) + be[n];
                acc[m][n][j] = sw;
                s1[m][j] += sw;
                s2[m][j] += sw * sw;
            }

    // reduce across the 16 lanes (r=0..15) that share the same rows
#pragma unroll
    for (int mask = 1; mask < 16; mask <<= 1) {
#pragma unroll
        for (int m = 0; m < 4; ++m)
#pragma unroll
            for (int j = 0; j < 4; ++j) {
                s1[m][j] += __shfl_xor(s1[m][j], mask, 64);
                s2[m][j] += __shfl_xor(s2[m][j], mask, 64);
            }
    }
    if (r == 0) {
#pragma unroll
        for (int m = 0; m < 4; ++m)
#pragma unroll
            for (int j = 0; j < 4; ++j) {
                int row = wrow * 64 + m * 16 + h * 4 + j;
                sred[0][wcol][row] = s1[m][j];
                sred[1][wcol][row] = s2[m][j];
            }
    }
    __syncthreads();

    const size_t orow_base = (size_t)brow * BM;
#pragma unroll
    for (int m = 0; m < 4; ++m)
#pragma unroll
        for (int j = 0; j < 4; ++j) {
            int row = wrow * 64 + m * 16 + h * 4 + j;
            float mu = (sred[0][0][row] + sred[0][1][row]) * (1.f / 128.f);
            float ex2 = (sred[1][0][row] + sred[1][1][row]) * (1.f / 128.f);
            float var = ex2 - mu * mu;
            float rs = rsqrtf(var + 1e-5f);
            float* orow = out + (orow_base + row) * N_DIM;
#pragma unroll
            for (int n = 0; n < 4; ++n) {
                int col = gcolbase + n * 16 + r;
                orow[col] = (acc[m][n][j] - mu) * rs * gwv[n] + gbv[n];
            }
        }
}

extern "C" void kernel_launch(void* const* d_in, const int* in_sizes, int n_in,
                              void* d_out, int out_size, void* d_ws, size_t ws_size,
                              hipStream_t stream) {
    const float* x        = (const float*)d_in[0];
    const float* weight   = (const float*)d_in[1];
    const float* bias_lin = (const float*)d_in[2];
    const float* bias_ex  = (const float*)d_in[3];
    const float* gn_w     = (const float*)d_in[4];
    const float* gn_b     = (const float*)d_in[5];
    float* out = (float*)d_out;

    ushort* xb = (ushort*)d_ws;                                // 8192*2048 bf16 = 32 MiB
    ushort* wb = xb + (size_t)M_DIM * K_DIM;                   // 4096*2048 bf16 = 16 MiB

    {
        int n8 = (M_DIM * K_DIM) / 8;
        f32_to_bf16_k<<<n8 / 256, 256, 0, stream>>>(x, xb, n8);
    }
    {
        int n8 = (N_DIM * K_DIM) / 8;
        f32_to_bf16_k<<<n8 / 256, 256, 0, stream>>>(weight, wb, n8);
    }

    dim3 grid(M_DIM / BM, N_DIM / BN);  // (64, 32)
    gemm_swish_gn<<<grid, 256, 0, stream>>>(xb, wb, bias_lin, bias_ex, gn_w, gn_b, out);
}

// Round 2
// 194.407 us; speedup vs baseline: 1.1788x; 1.1788x over previous
//
#include <hip/hip_runtime.h>

// Fused: z = x @ W^T + b_lin; y = swish(z) + b_ex; GroupNorm(32 groups) * gn_w + gn_b
// x: [8192, 2048] f32, W: [4096, 2048] f32, out: [8192, 4096] f32
// Round 2: 256x256 tile, BK=64, 8 waves, T1 XCD swizzle + T2 LDS XOR swizzle
// + T3/T4 counted-vmcnt 3-deep pipeline + T5 setprio. GN fused in epilogue.

typedef __attribute__((ext_vector_type(8))) short short8;
typedef __attribute__((ext_vector_type(4))) float f32x4;

#define M_DIM 8192
#define N_DIM 4096
#define K_DIM 2048
#define BM 256
#define BN 256
#define BK 64
#define NT (K_DIM / BK)  // 32

// ---------------- f32 -> bf16 (RNE) convert, 8 elems/thread ----------------
__global__ void f32_to_bf16_k(const float* __restrict__ in, ushort* __restrict__ out, int n8) {
    int i = blockIdx.x * blockDim.x + threadIdx.x;
    if (i >= n8) return;
    const float4* p = (const float4*)in + 2 * (size_t)i;
    float4 a = p[0], b = p[1];
    float v[8] = {a.x, a.y, a.z, a.w, b.x, b.y, b.z, b.w};
    ushort rr[8];
#pragma unroll
    for (int j = 0; j < 8; ++j) {
        unsigned u = __float_as_uint(v[j]);
        rr[j] = (ushort)((u + 0x7fffu + ((u >> 16) & 1u)) >> 16);  // RNE
    }
    uint4 o;
    o.x = (unsigned)rr[0] | ((unsigned)rr[1] << 16);
    o.y = (unsigned)rr[2] | ((unsigned)rr[3] << 16);
    o.z = (unsigned)rr[4] | ((unsigned)rr[5] << 16);
    o.w = (unsigned)rr[6] | ((unsigned)rr[7] << 16);
    ((uint4*)out)[i] = o;
}

// ---------------- fused GEMM + swish + GroupNorm ----------------
// 512 threads = 8 waves (2 M x 4 N). Wave owns 128x64 output (8x4 frags of 16x16).
// LDS: 2 dbuf x (A 256x64 + B 256x64) bf16 = 128 KiB (dynamic). Stats alias buf0.
__global__ __launch_bounds__(512, 2) void gemm_swish_gn(
    const ushort* __restrict__ xb, const ushort* __restrict__ wb,
    const float* __restrict__ bias_lin, const float* __restrict__ bias_extra,
    const float* __restrict__ gn_w, const float* __restrict__ gn_b,
    float* __restrict__ out)
{
    extern __shared__ __align__(16) ushort lds[];  // [2 buf][2 mat][16384]

    const int t = threadIdx.x;
    const int w = t >> 6;
    const int l = t & 63;
    const int wm = w >> 2;   // 0..1
    const int wn = w & 3;    // 0..3
    const int h = l >> 4;    // 0..3
    const int r = l & 15;    // 0..15

    // T1: XCD-aware swizzle (512 blocks, 512 % 8 == 0 -> simple bijective form)
    const int bid = blockIdx.x;
    const int id = (bid & 7) * 64 + (bid >> 3);
    const int brow = id & 31;   // M tile
    const int bcol = id >> 5;   // N tile (= 2 GroupNorm groups)

    // ---- staging addressing (T2 rule #21: linear LDS dest, inverse-swizzled global src)
    const int strow = t >> 3;                    // row within 64-row round block
    const int scb = (t & 7) << 4;                // byte col 0..112
    const int scbs = scb ^ ((strow & 7) << 4);   // swizzled byte col (involution)
    const ushort* srcA[4];
    const ushort* srcB[4];
#pragma unroll
    for (int rd = 0; rd < 4; ++rd) {
        srcA[rd] = xb + (size_t)(brow * BM + rd * 64 + strow) * K_DIM + (scbs >> 1);
        srcB[rd] = wb + (size_t)(bcol * BN + rd * 64 + strow) * K_DIM + (scbs >> 1);
    }
    const int dstoff = t * 8;  // ushort offset; +rd*4096 inside a 16384 buffer

#define STAGE(buf_) do {                                                          \
    _Pragma("unroll")                                                             \
    for (int rd = 0; rd < 4; ++rd) {                                              \
        __builtin_amdgcn_global_load_lds(                                         \
            (const __attribute__((address_space(1))) void*)srcA[rd],              \
            (__attribute__((address_space(3))) void*)&lds[((buf_)*2+0)*16384 + rd*4096 + dstoff], \
            16, 0, 0);                                                            \
        srcA[rd] += BK;                                                           \
    }                                                                             \
    _Pragma("unroll")                                                             \
    for (int rd = 0; rd < 4; ++rd) {                                              \
        __builtin_amdgcn_global_load_lds(                                         \
            (const __attribute__((address_space(1))) void*)srcB[rd],              \
            (__attribute__((address_space(3))) void*)&lds[((buf_)*2+1)*16384 + rd*4096 + dstoff], \
            16, 0, 0);                                                            \
        srcB[rd] += BK;                                                           \
    }                                                                             \
} while (0)

    f32x4 acc[8][4];
#pragma unroll
    for (int m = 0; m < 8; ++m)
#pragma unroll
        for (int n = 0; n < 4; ++n)
            acc[m][n] = f32x4{0.f, 0.f, 0.f, 0.f};

    STAGE(0);  // tile 0
    STAGE(1);  // tile 1   (16 loads in flight)

    const int xr = (r & 7) << 4;   // T2 read-side XOR
    const int aBase = wm * 128 + r;
    const int bBase = wn * 64 + r;

    short8 aF[8], bF[8];

#pragma unroll 1
    for (int tt = 0; tt < NT; ++tt) {
        // T4: counted vmcnt — tile tt landed, tile tt+1 (8 loads) stays in flight
        if (tt < NT - 1) asm volatile("s_waitcnt vmcnt(8)" ::: "memory");
        else             asm volatile("s_waitcnt vmcnt(0)" ::: "memory");
        __builtin_amdgcn_sched_barrier(0);
        __builtin_amdgcn_s_barrier();
        __builtin_amdgcn_sched_barrier(0);

        const int cur = tt & 1;
        const ushort* sA = &lds[(cur * 2 + 0) * 16384];
        const ushort* sB = &lds[(cur * 2 + 1) * 16384];

        // ---- P1: read A[m0..3], B[n0..1]; MFMA m0-3 x n0-1
#pragma unroll
        for (int m = 0; m < 4; ++m)
#pragma unroll
            for (int kk = 0; kk < 2; ++kk) {
                int row = aBase + m * 16;
                aF[m * 2 + kk] = *(const short8*)&sA[(row * 128 + ((kk * 64 + h * 16) ^ xr)) >> 1];
            }
#pragma unroll
        for (int n = 0; n < 2; ++n)
#pragma unroll
            for (int kk = 0; kk < 2; ++kk) {
                int row = bBase + n * 16;
                bF[n * 2 + kk] = *(const short8*)&sB[(row * 128 + ((kk * 64 + h * 16) ^ xr)) >> 1];
            }
        __builtin_amdgcn_s_setprio(1);
#pragma unroll
        for (int m = 0; m < 4; ++m)
#pragma unroll
            for (int n = 0; n < 2; ++n)
#pragma unroll
                for (int kk = 0; kk < 2; ++kk)
                    acc[m][n] = __builtin_amdgcn_mfma_f32_16x16x32_bf16(aF[m * 2 + kk], bF[n * 2 + kk], acc[m][n], 0, 0, 0);
        __builtin_amdgcn_s_setprio(0);

        // ---- P2: read B[n2..3]; MFMA m0-3 x n2-3
#pragma unroll
        for (int n = 2; n < 4; ++n)
#pragma unroll
            for (int kk = 0; kk < 2; ++kk) {
                int row = bBase + n * 16;
                bF[n * 2 + kk] = *(const short8*)&sB[(row * 128 + ((kk * 64 + h * 16) ^ xr)) >> 1];
            }
        __builtin_amdgcn_s_setprio(1);
#pragma unroll
        for (int m = 0; m < 4; ++m)
#pragma unroll
            for (int n = 2; n < 4; ++n)
#pragma unroll
                for (int kk = 0; kk < 2; ++kk)
                    acc[m][n] = __builtin_amdgcn_mfma_f32_16x16x32_bf16(aF[m * 2 + kk], bF[n * 2 + kk], acc[m][n], 0, 0, 0);
        __builtin_amdgcn_s_setprio(0);

        // ---- P3: read A[m4..7] (overwrite); MFMA m4-7 x n2-3
#pragma unroll
        for (int m = 4; m < 8; ++m)
#pragma unroll
            for (int kk = 0; kk < 2; ++kk) {
                int row = aBase + m * 16;
                aF[(m - 4) * 2 + kk] = *(const short8*)&sA[(row * 128 + ((kk * 64 + h * 16) ^ xr)) >> 1];
            }
        __builtin_amdgcn_s_setprio(1);
#pragma unroll
        for (int m = 4; m < 8; ++m)
#pragma unroll
            for (int n = 2; n < 4; ++n)
#pragma unroll
                for (int kk = 0; kk < 2; ++kk)
                    acc[m][n] = __builtin_amdgcn_mfma_f32_16x16x32_bf16(aF[(m - 4) * 2 + kk], bF[n * 2 + kk], acc[m][n], 0, 0, 0);
        __builtin_amdgcn_s_setprio(0);

        // all 24 ds_reads of this tile are consumed above -> buffer free after barrier
        __builtin_amdgcn_s_barrier();
        if (tt + 2 < NT) STAGE(tt & 1);  // stage tile tt+2 into the buffer just freed

        // ---- P4: register-only MFMA m4-7 x n0-1 (covers the stage issue cost)
        __builtin_amdgcn_s_setprio(1);
#pragma unroll
        for (int m = 4; m < 8; ++m)
#pragma unroll
            for (int n = 0; n < 2; ++n)
#pragma unroll
                for (int kk = 0; kk < 2; ++kk)
                    acc[m][n] = __builtin_amdgcn_mfma_f32_16x16x32_bf16(aF[(m - 4) * 2 + kk], bF[n * 2 + kk], acc[m][n], 0, 0, 0);
        __builtin_amdgcn_s_setprio(0);
    }

    // ---- epilogue: bias + swish + extra bias, GroupNorm per 128-col group ----
    // acc[m][n][j]: row = wm*128 + m*16 + h*4 + j, col = wn*64 + n*16 + r
    const int colbase = bcol * BN + wn * 64;
    float bl[4], be[4], gwv[4], gbv[4];
#pragma unroll
    for (int n = 0; n < 4; ++n) {
        int col = colbase + n * 16 + r;
        bl[n] = bias_lin[col];
        be[n] = bias_extra[col];
        gwv[n] = gn_w[col];
        gbv[n] = gn_b[col];
    }

    float s1[8][4], s2[8][4];
#pragma unroll
    for (int m = 0; m < 8; ++m)
#pragma unroll
        for (int j = 0; j < 4; ++j) { s1[m][j] = 0.f; s2[m][j] = 0.f; }

#pragma unroll
    for (int m = 0; m < 8; ++m)
#pragma unroll
        for (int n = 0; n < 4; ++n)
#pragma unroll
            for (int j = 0; j < 4; ++j) {
                float z = acc[m][n][j] + bl[n];
                float sw = z / (1.f + __expf(-z)) + be[n];
                acc[m][n][j] = sw;
                s1[m][j] += sw;
                s2[m][j] += sw * sw;
            }

    // reduce over the 16 lanes (r) sharing the same rows
#pragma unroll
    for (int mask = 1; mask < 16; mask <<= 1) {
#pragma unroll
        for (int m = 0; m < 8; ++m)
#pragma unroll
            for (int j = 0; j < 4; ++j) {
                s1[m][j] += __shfl_xor(s1[m][j], mask, 16);
                s2[m][j] += __shfl_xor(s2[m][j], mask, 16);
            }
    }

    // stats exchange: alias first 8 KiB of LDS (tile data dead after final barrier)
    float* sred = (float*)lds;  // [2 stat][2 group-half][2 wave-pair][256 rows]
    const int gh = wn >> 1;     // which 128-col group within the tile
    const int p = wn & 1;       // which wave of the pair
    if (r == 0) {
#pragma unroll
        for (int m = 0; m < 8; ++m)
#pragma unroll
            for (int j = 0; j < 4; ++j) {
                int row = wm * 128 + m * 16 + h * 4 + j;
                sred[((0 * 2 + gh) * 2 + p) * 256 + row] = s1[m][j];
                sred[((1 * 2 + gh) * 2 + p) * 256 + row] = s2[m][j];
            }
    }
    __syncthreads();

    const size_t orow0 = (size_t)brow * BM;
#pragma unroll
    for (int m = 0; m < 8; ++m)
#pragma unroll
        for (int j = 0; j < 4; ++j) {
            int row = wm * 128 + m * 16 + h * 4 + j;
            float mu = (sred[((0 * 2 + gh) * 2 + 0) * 256 + row] +
                        sred[((0 * 2 + gh) * 2 + 1) * 256 + row]) * (1.f / 128.f);
            float ex2 = (sred[((1 * 2 + gh) * 2 + 0) * 256 + row] +
                         sred[((1 * 2 + gh) * 2 + 1) * 256 + row]) * (1.f / 128.f);
            float var = ex2 - mu * mu;
            float rs = rsqrtf(var + 1e-5f);
            float* orow = out + (orow0 + row) * N_DIM;
#pragma unroll
            for (int n = 0; n < 4; ++n) {
                int col = colbase + n * 16 + r;
                orow[col] = (acc[m][n][j] - mu) * rs * gwv[n] + gbv[n];
            }
        }
}

extern "C" void kernel_launch(void* const* d_in, const int* in_sizes, int n_in,
                              void* d_out, int out_size, void* d_ws, size_t ws_size,
                              hipStream_t stream) {
    const float* x        = (const float*)d_in[0];
    const float* weight   = (const float*)d_in[1];
    const float* bias_lin = (const float*)d_in[2];
    const float* bias_ex  = (const float*)d_in[3];
    const float* gn_w     = (const float*)d_in[4];
    const float* gn_b     = (const float*)d_in[5];
    float* out = (float*)d_out;

    ushort* xb = (ushort*)d_ws;                     // 32 MiB bf16
    ushort* wb = xb + (size_t)M_DIM * K_DIM;        // 16 MiB bf16

    {
        int n8 = (M_DIM * K_DIM) / 8;
        f32_to_bf16_k<<<n8 / 256, 256, 0, stream>>>(x, xb, n8);
    }
    {
        int n8 = (N_DIM * K_DIM) / 8;
        f32_to_bf16_k<<<n8 / 256, 256, 0, stream>>>(weight, wb, n8);
    }

    // 128 KiB dynamic LDS (> 64 KiB default cap) — raise the limit; harmless if already set.
    static_assert(2 * 2 * 16384 * sizeof(ushort) == 131072, "lds size");
    (void)hipFuncSetAttribute((const void*)gemm_swish_gn,
                              hipFuncAttributeMaxDynamicSharedMemorySize, 131072);

    dim3 grid((M_DIM / BM) * (N_DIM / BN));  // 512 blocks
    gemm_swish_gn<<<grid, 512, 131072, stream>>>(xb, wb, bias_lin, bias_ex, gn_w, gn_b, out);
}